// Round 4
// baseline (14057.825 us; speedup 1.0000x reference)
//
#include <hip/hip_runtime.h>

// ---------------- problem constants ----------------
#define TT   2048          // timesteps
#define NB   16            // batch
#define HH   512           // hidden
#define NSL  32            // workgroups per layer (hidden slices)
#define HSL  16            // hidden units per slice
#define KW   128           // K-range per wave (4 waves * 128 = 512)
#define Y_SZ (NB*TT*32)    // y output elements
#define SENT 0xFFFFFFFFFFFFFFFFULL   // sentinel: 4x bf16 NaN, unreachable as data

typedef __attribute__((ext_vector_type(8))) short bf16x8;
typedef __attribute__((ext_vector_type(4))) float f32x4;
typedef unsigned long long ull;

// ---------------- workspace layout ----------------
// Four t-indexed h arrays (hi/lo bf16 split, layers 1..2), slot s = h before
// step s; slot 0 = zeros; all other slots pre-set to SENT by memset(0xFF).
#define HARR  ((size_t)(TT+1)*NB*HH)   // ushorts per h array

__device__ __forceinline__ unsigned short f2bf(float x){
  unsigned u = __float_as_uint(x);
  return (unsigned short)((u + 0x7FFFu + ((u >> 16) & 1u)) >> 16);
}
__device__ __forceinline__ float bf2f(unsigned short b){
  return __uint_as_float(((unsigned)b) << 16);
}
__device__ __forceinline__ float sigm(float v){ return 1.0f / (1.0f + __expf(-v)); }
__device__ __forceinline__ float tanh_f(float v){
  float a = fabsf(v);
  float e = __expf(-2.0f * a);
  float t = (1.0f - e) / (1.0f + e);
  return v < 0.0f ? -t : t;
}
__device__ __forceinline__ void split8(const float* __restrict__ p, bf16x8& hi, bf16x8& lo){
#pragma unroll
  for (int j = 0; j < 8; ++j){
    float w = p[j];
    unsigned short h = f2bf(w);
    hi[j] = (short)h;
    lo[j] = (short)f2bf(w - bf2f(h));
  }
}
__device__ __forceinline__ ull ldc(const ull* p){   // coherent 8B load (sc0 sc1)
  return __hip_atomic_load(p, __ATOMIC_RELAXED, __HIP_MEMORY_SCOPE_AGENT);
}
__device__ __forceinline__ bf16x8 mk(ull a, ull b){
  union { ull u[2]; bf16x8 v; } r; r.u[0] = a; r.u[1] = b; return r.v;
}

// =====================================================================
// Persistent 2-layer LSTM. 64 WGs: wg 0..31 = layer0, 32..63 = layer1.
// Weights pinned in VGPRs as bf16 hi/lo fragments; 3-pass split MFMA.
// Flag-free sync: consumers poll the h data itself for the sentinel.
// Per-step chain = ONE coherence hop (publish store -> consumer load).
// =====================================================================
__global__ __launch_bounds__(256, 1) void lstm_persist(
    const float* __restrict__ x,
    const float* __restrict__ w_ih0, const float* __restrict__ w_hh0,
    const float* __restrict__ b_ih0, const float* __restrict__ b_hh0,
    const float* __restrict__ w_ih1, const float* __restrict__ w_hh1,
    const float* __restrict__ b_ih1, const float* __restrict__ b_hh1,
    float* __restrict__ out, unsigned char* __restrict__ ws)
{
  unsigned short* Hhi1 = (unsigned short*)ws;
  unsigned short* Hlo1 = Hhi1 + HARR;
  unsigned short* Hhi2 = Hlo1 + HARR;
  unsigned short* Hlo2 = Hhi2 + HARR;

  const int tid  = threadIdx.x;
  const int lane = tid & 63;
  const int wv   = tid >> 6;       // wave 0..3 -> K slice
  const int m16  = lane & 15;
  const int quad = lane >> 4;
  const int wg    = blockIdx.x;
  const int layer = wg >> 5;
  const int sl    = wg & 31;
  const int j0    = sl * HSL;
  const int kwb   = wv * KW;

  const float* Wh  = layer ? w_hh1 : w_hh0;
  const float* biL = layer ? b_ih1 : b_ih0;
  const float* bhL = layer ? b_hh1 : b_hh0;

  // ---- recurrent weights -> registers (B-frag: n=lane&15, k=quad*8+j)
  bf16x8 Bh_hi[4][4], Bh_lo[4][4];
#pragma unroll
  for (int g = 0; g < 4; ++g)
#pragma unroll
    for (int c = 0; c < 4; ++c){
      int row = g*HH + j0 + m16;
      int k0  = kwb + c*32 + quad*8;
      split8(Wh + (size_t)row*HH + k0, Bh_hi[g][c], Bh_lo[g][c]);
    }
  bf16x8 Bi_hi[4][4], Bi_lo[4][4];
  if (layer){
#pragma unroll
    for (int g = 0; g < 4; ++g)
#pragma unroll
      for (int c = 0; c < 4; ++c){
        int row = g*HH + j0 + m16;
        int k0  = kwb + c*32 + quad*8;
        split8(w_ih1 + (size_t)row*HH + k0, Bi_hi[g][c], Bi_lo[g][c]);
      }
  } else if (wv == 0){
#pragma unroll
    for (int g = 0; g < 4; ++g){
      int row = g*HH + j0 + m16;
      split8(w_ih0 + (size_t)row*32 + quad*8, Bi_hi[g][0], Bi_lo[g][0]);
    }
  }

  const int eb = tid >> 4;
  const int ej = tid & 15;
  float bias[4];
#pragma unroll
  for (int g = 0; g < 4; ++g){
    int r = g*HH + j0 + ej;
    bias[g] = biL[r] + bhL[r];
  }

  float cst = 0.0f;

  __shared__ float P[2][4][4][16][16];   // parity-double-buffered partials

  const unsigned short* RecHi = layer ? Hhi2 : Hhi1;
  const unsigned short* RecLo = layer ? Hlo2 : Hlo1;
  unsigned short* OutHi = layer ? Hhi2 : Hhi1;
  unsigned short* OutLo = layer ? Hlo2 : Hlo1;

  for (int t = 0; t < TT; ++t){
    const int par = t & 1;
    f32x4 acc[4];
#pragma unroll
    for (int g = 0; g < 4; ++g) acc[g] = f32x4{0.f, 0.f, 0.f, 0.f};

    // ---- issue ALL fragment loads up front (max MLP, one round trip) ----
    const size_t rbase = ((size_t)t*NB + m16)*HH + kwb + quad*8;
    const ull* qh = (const ull*)(RecHi + rbase);
    const ull* ql = (const ull*)(RecLo + rbase);
    ull uh[8], ulo[8];
#pragma unroll
    for (int c = 0; c < 4; ++c){
      uh[2*c]    = ldc(qh + c*8);
      uh[2*c+1]  = ldc(qh + c*8 + 1);
      ulo[2*c]   = ldc(ql + c*8);
      ulo[2*c+1] = ldc(ql + c*8 + 1);
    }
    ull vh[8], vlo[8];
    const ull* ph = nullptr; const ull* pl = nullptr;
    if (layer){
      const size_t ibase = ((size_t)(t+1)*NB + m16)*HH + kwb + quad*8;
      ph = (const ull*)(Hhi1 + ibase);
      pl = (const ull*)(Hlo1 + ibase);
#pragma unroll
      for (int c = 0; c < 4; ++c){
        vh[2*c]    = ldc(ph + c*8);
        vh[2*c+1]  = ldc(ph + c*8 + 1);
        vlo[2*c]   = ldc(pl + c*8);
        vlo[2*c+1] = ldc(pl + c*8 + 1);
      }
    }

    // ---- layer0 x-term overlaps the poll latency ----
    if (layer == 0 && wv == 0){
      const float* xp = x + ((size_t)m16*TT + t)*32 + quad*8;
      bf16x8 ah, al;
#pragma unroll
      for (int j = 0; j < 8; ++j){
        float v = xp[j];
        unsigned short h = f2bf(v);
        ah[j] = (short)h;
        al[j] = (short)f2bf(v - bf2f(h));
      }
#pragma unroll
      for (int g = 0; g < 4; ++g){
        acc[g] = __builtin_amdgcn_mfma_f32_16x16x32_bf16(ah, Bi_hi[g][0], acc[g], 0, 0, 0);
        acc[g] = __builtin_amdgcn_mfma_f32_16x16x32_bf16(al, Bi_hi[g][0], acc[g], 0, 0, 0);
        acc[g] = __builtin_amdgcn_mfma_f32_16x16x32_bf16(ah, Bi_lo[g][0], acc[g], 0, 0, 0);
      }
    }

    // ---- sentinel retry-scan: reload only not-yet-published chunks ----
    {
      long it = 0;
      while (true){
        bool any = false;
#pragma unroll
        for (int i = 0; i < 8; ++i){
          any = any | (uh[i] == SENT) | (ulo[i] == SENT);
          if (layer) any = any | (vh[i] == SENT) | (vlo[i] == SENT);
        }
        if (!any || ++it > 5000000L) break;
#pragma unroll
        for (int i = 0; i < 8; ++i){
          if (uh[i]  == SENT) uh[i]  = ldc(qh + (i>>1)*8 + (i&1));
          if (ulo[i] == SENT) ulo[i] = ldc(ql + (i>>1)*8 + (i&1));
          if (layer){
            if (vh[i]  == SENT) vh[i]  = ldc(ph + (i>>1)*8 + (i&1));
            if (vlo[i] == SENT) vlo[i] = ldc(pl + (i>>1)*8 + (i&1));
          }
        }
      }
    }

    // ---- matmuls ----
    if (layer){
#pragma unroll
      for (int c = 0; c < 4; ++c){
        bf16x8 ah = mk(vh[2*c], vh[2*c+1]);
        bf16x8 al = mk(vlo[2*c], vlo[2*c+1]);
#pragma unroll
        for (int g = 0; g < 4; ++g){
          acc[g] = __builtin_amdgcn_mfma_f32_16x16x32_bf16(ah, Bi_hi[g][c], acc[g], 0, 0, 0);
          acc[g] = __builtin_amdgcn_mfma_f32_16x16x32_bf16(al, Bi_hi[g][c], acc[g], 0, 0, 0);
          acc[g] = __builtin_amdgcn_mfma_f32_16x16x32_bf16(ah, Bi_lo[g][c], acc[g], 0, 0, 0);
        }
      }
    }
#pragma unroll
    for (int c = 0; c < 4; ++c){
      bf16x8 ah = mk(uh[2*c], uh[2*c+1]);
      bf16x8 al = mk(ulo[2*c], ulo[2*c+1]);
#pragma unroll
      for (int g = 0; g < 4; ++g){
        acc[g] = __builtin_amdgcn_mfma_f32_16x16x32_bf16(ah, Bh_hi[g][c], acc[g], 0, 0, 0);
        acc[g] = __builtin_amdgcn_mfma_f32_16x16x32_bf16(al, Bh_hi[g][c], acc[g], 0, 0, 0);
        acc[g] = __builtin_amdgcn_mfma_f32_16x16x32_bf16(ah, Bh_lo[g][c], acc[g], 0, 0, 0);
      }
    }

    // ---- K-reduction across waves via LDS (parity buffer, ONE barrier) ----
#pragma unroll
    for (int g = 0; g < 4; ++g)
#pragma unroll
      for (int r = 0; r < 4; ++r)
        P[par][wv][g][quad*4 + r][m16] = acc[g][r];
    __syncthreads();

    float G[4];
#pragma unroll
    for (int g = 0; g < 4; ++g)
      G[g] = P[par][0][g][eb][ej] + P[par][1][g][eb][ej]
           + P[par][2][g][eb][ej] + P[par][3][g][eb][ej] + bias[g];

    // ---- LSTM cell (fp32) ----
    float gi = sigm(G[0]);
    float gf = sigm(G[1]);
    float gc = tanh_f(G[2]);
    float go = sigm(G[3]);
    cst = gf*cst + gi*gc;
    float h = go * tanh_f(cst);

    // ---- publish h (atomic 8B chunks; no drain, no flag, no barrier) ----
    unsigned short hhi = f2bf(h);
    unsigned short hlo = f2bf(h - bf2f(hhi));
    ull h1s = (ull)(unsigned short)__shfl_down((int)hhi, 1, 64);
    ull h2s = (ull)(unsigned short)__shfl_down((int)hhi, 2, 64);
    ull h3s = (ull)(unsigned short)__shfl_down((int)hhi, 3, 64);
    ull l1s = (ull)(unsigned short)__shfl_down((int)hlo, 1, 64);
    ull l2s = (ull)(unsigned short)__shfl_down((int)hlo, 2, 64);
    ull l3s = (ull)(unsigned short)__shfl_down((int)hlo, 3, 64);
    if ((ej & 3) == 0){
      size_t po = (((size_t)(t+1)*NB + eb)*HH + (unsigned)(j0 + ej)) >> 2;
      __hip_atomic_store((ull*)OutHi + po,
                         (ull)hhi | (h1s << 16) | (h2s << 32) | (h3s << 48),
                         __ATOMIC_RELAXED, __HIP_MEMORY_SCOPE_AGENT);
      __hip_atomic_store((ull*)OutLo + po,
                         (ull)hlo | (l1s << 16) | (l2s << 32) | (l3s << 48),
                         __ATOMIC_RELAXED, __HIP_MEMORY_SCOPE_AGENT);
    }

    if (t == TT-1){
      size_t o = (size_t)layer*NB*HH + (size_t)eb*HH + (j0 + ej);
      out[Y_SZ + o] = h;
      out[Y_SZ + 2*NB*HH + o] = cst;
    }
  }
}

// =====================================================================
// y = h2 @ w_out^T + b_out   (parallel epilogue, one block per timestep)
// =====================================================================
__global__ __launch_bounds__(256, 1) void y_proj(
    const unsigned short* __restrict__ Hhi2, const unsigned short* __restrict__ Hlo2,
    const float* __restrict__ w_out, const float* __restrict__ b_out,
    float* __restrict__ out)
{
  __shared__ float hsh[NB][HH + 1];
  __shared__ float wsh[32][HH + 1];
  const int tid = threadIdx.x;
  const int t = blockIdx.x;

  for (int i = tid; i < 32*HH; i += 256){
    int o = i >> 9, k = i & (HH-1);
    wsh[o][k] = w_out[i];
  }
  for (int i = tid; i < NB*HH; i += 256){
    int b = i >> 9, k = i & (HH-1);
    size_t off = ((size_t)(t+1)*NB + b)*HH + k;
    hsh[b][k] = bf2f(Hhi2[off]) + bf2f(Hlo2[off]);
  }
  __syncthreads();

  const int o = tid & 31, bg = tid >> 5;
  float a0 = 0.f, a1 = 0.f;
  for (int k = 0; k < HH; ++k){
    float w = wsh[o][k];
    a0 += w * hsh[bg][k];
    a1 += w * hsh[bg + 8][k];
  }
  float bo = b_out[o];
  out[((size_t)bg*TT + t)*32 + o] = a0 + bo;
  out[((size_t)(bg+8)*TT + t)*32 + o] = a1 + bo;
}

extern "C" void kernel_launch(void* const* d_in, const int* in_sizes, int n_in,
                              void* d_out, int out_size, void* d_ws, size_t ws_size,
                              hipStream_t stream)
{
  (void)in_sizes; (void)n_in; (void)out_size;
  const float* x     = (const float*)d_in[0];
  const float* w_ih0 = (const float*)d_in[1];
  const float* w_hh0 = (const float*)d_in[2];
  const float* b_ih0 = (const float*)d_in[3];
  const float* b_hh0 = (const float*)d_in[4];
  const float* w_ih1 = (const float*)d_in[5];
  const float* w_hh1 = (const float*)d_in[6];
  const float* b_ih1 = (const float*)d_in[7];
  const float* b_hh1 = (const float*)d_in[8];
  const float* w_out = (const float*)d_in[9];
  const float* b_out = (const float*)d_in[10];
  float* out = (float*)d_out;
  unsigned char* ws = (unsigned char*)d_ws;

  const size_t need = 4*HARR*sizeof(unsigned short);
  if (ws_size < need) return;

  // sentinel-fill all h slots, then zero slot 0 of each array
  hipMemsetAsync(ws, 0xFF, need, stream);
  for (int a = 0; a < 4; ++a)
    hipMemsetAsync(ws + (size_t)a*HARR*2, 0, (size_t)NB*HH*2, stream);

  lstm_persist<<<dim3(2*NSL), dim3(256), 0, stream>>>(
      x, w_ih0, w_hh0, b_ih0, b_hh0, w_ih1, w_hh1, b_ih1, b_hh1, out, ws);

  const unsigned short* Hhi2 = (const unsigned short*)ws + 2*HARR;
  const unsigned short* Hlo2 = (const unsigned short*)ws + 3*HARR;
  y_proj<<<dim3(TT), dim3(256), 0, stream>>>(Hhi2, Hlo2, w_out, b_out, out);
}

// Round 6
// 10780.560 us; speedup vs baseline: 1.3040x; 1.3040x over previous
//
#include <hip/hip_runtime.h>

// ---------------- problem constants ----------------
#define TT   2048
#define NB   16
#define HH   512
#define NSL  32            // WG slices per layer
#define HSL  16            // hidden units per slice
#define KW   128           // K-range per wave
#define Y_SZ (NB*TT*32)
#define RING 256
#define RM   255

typedef __attribute__((ext_vector_type(8))) short bf16x8;
typedef __attribute__((ext_vector_type(4))) float f32x4;
typedef __attribute__((ext_vector_type(4))) unsigned u32x4;
typedef unsigned long long ull;

// ---------------- workspace layout (bytes) ----------------
#define OFF_XCCV 0u                     /* 64 u32: role -> xcc|0x100 */
#define OFF_MODE 256u                   /* 1 u32: mode|0x100 */
#define OFF_PROG 512u                   /* 32 u32: layer1 progress */
#define OFF_F1L  4096u
#define FLB      (4u*RING*32u*4u)       /* 128KB per flag array [4][RING][32] */
#define OFF_F1X  (OFF_F1L + FLB)
#define OFF_F2L  (OFF_F1X + FLB)
#define OFF_F2X  (OFF_F2L + FLB)
#define OFF_ZEND (OFF_F2X + FLB)
#define RSLOT    ((size_t)NB*HH)        /* ushorts per ring slot */
#define RB       ((size_t)RING*RSLOT*2) /* 4MB per ring array */
#define OFF_H1LH ((size_t)(1u<<20))
#define OFF_H1LL (OFF_H1LH + RB)
#define OFF_H1XH (OFF_H1LL + RB)
#define OFF_H1XL (OFF_H1XH + RB)
#define OFF_H2LH (OFF_H1XL + RB)
#define OFF_H2LL (OFF_H2LH + RB)
#define OFF_H2XH (OFF_H2LL + RB)
#define OFF_H2XL (OFF_H2XH + RB)
#define FB       ((size_t)TT*RSLOT*2)   /* 32MB full h2 history */
#define OFF_H2FH (OFF_H2XL + RB)
#define OFF_H2FL (OFF_H2FH + FB)
#define WS_NEED  (OFF_H2FL + FB)

__device__ __forceinline__ unsigned short f2bf(float x){
  unsigned u = __float_as_uint(x);
  return (unsigned short)((u + 0x7FFFu + ((u >> 16) & 1u)) >> 16);
}
__device__ __forceinline__ float bf2f(unsigned short b){
  return __uint_as_float(((unsigned)b) << 16);
}
__device__ __forceinline__ float sigm(float v){ return 1.0f / (1.0f + __expf(-v)); }
__device__ __forceinline__ float tanh_f(float v){
  float a = fabsf(v);
  float e = __expf(-2.0f * a);
  float t = (1.0f - e) / (1.0f + e);
  return v < 0.0f ? -t : t;
}
__device__ __forceinline__ void split8(const float* __restrict__ p, bf16x8& hi, bf16x8& lo){
#pragma unroll
  for (int j = 0; j < 8; ++j){
    float w = p[j];
    unsigned short h = f2bf(w);
    hi[j] = (short)h;
    lo[j] = (short)f2bf(w - bf2f(h));
  }
}
__device__ __forceinline__ bf16x8 mk(ull a, ull b){
  union { ull u[2]; bf16x8 v; } r; r.u[0] = a; r.u[1] = b; return r.v;
}
__device__ __forceinline__ bf16x8 asfrag(u32x4 v){
  union { u32x4 u; bf16x8 b; } r; r.u = v; return r.b;
}
// ---- proven LIC (agent-scope) primitives: __hip_atomic intrinsics ----
__device__ __forceinline__ ull ld64_lic(const ull* p){
  return __hip_atomic_load(p, __ATOMIC_RELAXED, __HIP_MEMORY_SCOPE_AGENT);
}
__device__ __forceinline__ unsigned ld32_lic(const unsigned* p){
  return __hip_atomic_load(p, __ATOMIC_RELAXED, __HIP_MEMORY_SCOPE_AGENT);
}
__device__ __forceinline__ void st64_lic(ull* p, ull v){
  __hip_atomic_store(p, v, __ATOMIC_RELAXED, __HIP_MEMORY_SCOPE_AGENT);
}
__device__ __forceinline__ void st32_lic(unsigned* p, unsigned v){
  __hip_atomic_store(p, v, __ATOMIC_RELAXED, __HIP_MEMORY_SCOPE_AGENT);
}
__device__ __forceinline__ bf16x8 ld_frag_lic(const unsigned short* p){
  return mk(ld64_lic((const ull*)p), ld64_lic((const ull*)p + 1));
}
// ---- XCD-local primitives: invalidate L1, then plain (L2-served) access ----
__device__ __forceinline__ unsigned ld32_l2(const unsigned* p){
  unsigned r;
  asm volatile("buffer_inv sc0\n\t"
               "global_load_dword %0, %1, off\n\t"
               "s_waitcnt vmcnt(0)"
               : "=&v"(r) : "v"(p) : "memory");
  return r;
}
// 4 hi + 4 lo 16B frags from the XCD L2 (chunks 64B apart), one wait
__device__ __forceinline__ void ld8_l2(const void* ph, const void* pl, u32x4* r){
  asm volatile(
    "buffer_inv sc0\n\t"
    "global_load_dwordx4 %0, %8, off\n\t"
    "global_load_dwordx4 %1, %8, off offset:64\n\t"
    "global_load_dwordx4 %2, %8, off offset:128\n\t"
    "global_load_dwordx4 %3, %8, off offset:192\n\t"
    "global_load_dwordx4 %4, %9, off\n\t"
    "global_load_dwordx4 %5, %9, off offset:64\n\t"
    "global_load_dwordx4 %6, %9, off offset:128\n\t"
    "global_load_dwordx4 %7, %9, off offset:192\n\t"
    "s_waitcnt vmcnt(0)"
    : "=&v"(r[0]),"=&v"(r[1]),"=&v"(r[2]),"=&v"(r[3]),
      "=&v"(r[4]),"=&v"(r[5]),"=&v"(r[6]),"=&v"(r[7])
    : "v"(ph), "v"(pl) : "memory");
}
__device__ __forceinline__ void st64_pl(void* p, ull v){
  asm volatile("global_store_dwordx2 %0, %1, off" :: "v"(p), "v"(v) : "memory");
}
__device__ __forceinline__ void st32_pl(unsigned* p, unsigned v){
  asm volatile("global_store_dword %0, %1, off" :: "v"(p), "v"(v) : "memory");
}

// flag wait; returns 1 if satisfied via local path, 0 via LIC (=> demote)
__device__ __forceinline__ int wait_hy(const unsigned* bL, const unsigned* bX,
                                       unsigned expect, int lane, int lmode, long& bud){
  if (!lmode){
    bool ok = (lane >= 32);
    while (__ballot(!ok) != 0ULL){
      if (!ok) ok = (ld32_lic(bX + lane) == expect);
      if (--bud < 0) return 0;
    }
    return 0;
  }
  bool okL = (lane >= 32);
  int k = 0;
  while (true){
    if (__ballot(!okL) == 0ULL) return 1;
    if (!okL) okL = (ld32_l2(bL + lane) == expect);
    if ((++k & 15) == 0){
      bool okX = (lane >= 32);
      if (!okX) okX = (ld32_lic(bX + lane) == expect);
      if (__ballot(!okX) == 0ULL){
        if (!okL) okL = (ld32_l2(bL + lane) == expect);
        return (__ballot(!okL) == 0ULL) ? 1 : 0;   // local stale => demote
      }
    }
    if (--bud < 0) return 0;
  }
}

// =====================================================================
// Persistent 2-layer LSTM, XCD-local coherence with verified fallback.
// Static roles: blockIdx%8==0 -> layer0 slice, %8==1 -> layer1, rest exit.
// Producers dual-publish (plain->XCD L2, atomic->LIC); consumers use the
// local path only when placement is verified AND local flags track LIC.
// =====================================================================
__global__ __launch_bounds__(256, 1) void lstm_persist(
    const float* __restrict__ x,
    const float* __restrict__ w_ih0, const float* __restrict__ w_hh0,
    const float* __restrict__ b_ih0, const float* __restrict__ b_hh0,
    const float* __restrict__ w_ih1, const float* __restrict__ w_hh1,
    const float* __restrict__ b_ih1, const float* __restrict__ b_hh1,
    float* __restrict__ out, unsigned char* __restrict__ ws)
{
  unsigned* XCCV = (unsigned*)(ws + OFF_XCCV);
  unsigned* MODE = (unsigned*)(ws + OFF_MODE);
  unsigned* PROG = (unsigned*)(ws + OFF_PROG);
  unsigned* F1L  = (unsigned*)(ws + OFF_F1L);
  unsigned* F1X  = (unsigned*)(ws + OFF_F1X);
  unsigned* F2L  = (unsigned*)(ws + OFF_F2L);
  unsigned* F2X  = (unsigned*)(ws + OFF_F2X);
  unsigned short* H1Lh = (unsigned short*)(ws + OFF_H1LH);
  unsigned short* H1Ll = (unsigned short*)(ws + OFF_H1LL);
  unsigned short* H1Xh = (unsigned short*)(ws + OFF_H1XH);
  unsigned short* H1Xl = (unsigned short*)(ws + OFF_H1XL);
  unsigned short* H2Lh = (unsigned short*)(ws + OFF_H2LH);
  unsigned short* H2Ll = (unsigned short*)(ws + OFF_H2LL);
  unsigned short* H2Xh = (unsigned short*)(ws + OFF_H2XH);
  unsigned short* H2Xl = (unsigned short*)(ws + OFF_H2XL);
  unsigned short* H2Fh = (unsigned short*)(ws + OFF_H2FH);
  unsigned short* H2Fl = (unsigned short*)(ws + OFF_H2FL);

  const int tid  = threadIdx.x;
  const int lane = tid & 63;
  const int wv   = tid >> 6;
  const int m16  = lane & 15;
  const int quad = lane >> 4;

  // ---- static role: blockIdx%8 picks XCD stream (heuristic; verified below)
  const int bid = blockIdx.x;
  const int xs  = bid & 7;
  const int pos = bid >> 3;
  if (xs >= 2 || pos >= NSL) return;      // non-role
  const int layer = xs;
  const int sl    = pos;
  const int role  = layer * NSL + sl;
  const int j0    = sl * HSL;
  const int kwb   = wv * KW;

  long bud = 3000000;                     // cumulative spin budget (fail fast)

  // ---- publish own XCC id; block 0 verifies placement and broadcasts mode
  if (tid == 0){
    unsigned xcc = 0xDEAD;
    asm volatile("s_getreg_b32 %0, hwreg(HW_REG_XCC_ID)" : "=s"(xcc));
    st32_lic(XCCV + role, (xcc & 255u) | 0x100u);
  }
  __syncthreads();
  if (bid == 0 && wv == 0){
    bool got = false; unsigned v = 0;
    long b2 = 2000000;
    while (true){
      if (!got){ v = ld32_lic(XCCV + lane); got = (v & 0x100u) != 0u; }
      if (__ballot(!got) == 0ULL) break;
      if (--b2 < 0) break;
    }
    unsigned v0  = (unsigned)__shfl((int)v, 0, 64);
    unsigned v32 = (unsigned)__shfl((int)v, 32, 64);
    bool ok = got && ((lane < 32) ? (v == v0) : (v == v32));
    unsigned mode = (__ballot(!ok) == 0ULL) ? 1u : 0u;
    if (lane == 0) st32_lic(MODE, mode | 0x100u);
  }
  __shared__ unsigned s_mode;
  if (tid == 0){
    unsigned m = 0; long b3 = 2000000;
    do { m = ld32_lic(MODE); } while (!(m & 0x100u) && --b3 > 0);
    s_mode = m;
  }
  __syncthreads();
  int lmode = ((s_mode & 0x100u) && (s_mode & 1u)) ? 1 : 0;

  const float* Wh  = layer ? w_hh1 : w_hh0;
  const float* biL = layer ? b_ih1 : b_ih0;
  const float* bhL = layer ? b_hh1 : b_hh0;

  // ---- weights -> registers (B-frag: n=lane&15, k=quad*8+j)
  bf16x8 Bh_hi[4][4], Bh_lo[4][4];
#pragma unroll
  for (int g = 0; g < 4; ++g)
#pragma unroll
    for (int c = 0; c < 4; ++c){
      int row = g*HH + j0 + m16;
      int k0  = kwb + c*32 + quad*8;
      split8(Wh + (size_t)row*HH + k0, Bh_hi[g][c], Bh_lo[g][c]);
    }
  bf16x8 Bi_hi[4][4], Bi_lo[4][4];
  if (layer){
#pragma unroll
    for (int g = 0; g < 4; ++g)
#pragma unroll
      for (int c = 0; c < 4; ++c){
        int row = g*HH + j0 + m16;
        int k0  = kwb + c*32 + quad*8;
        split8(w_ih1 + (size_t)row*HH + k0, Bi_hi[g][c], Bi_lo[g][c]);
      }
  } else if (wv == 0){
#pragma unroll
    for (int g = 0; g < 4; ++g){
      int row = g*HH + j0 + m16;
      split8(w_ih0 + (size_t)row*32 + quad*8, Bi_hi[g][0], Bi_lo[g][0]);
    }
  }

  const int eb = tid >> 4;
  const int ej = tid & 15;
  float bias[4];
#pragma unroll
  for (int g = 0; g < 4; ++g){
    int r = g*HH + j0 + ej;
    bias[g] = biL[r] + bhL[r];
  }

  float cst = 0.0f;
  __shared__ float P[4][4][16][16];
  unsigned minp = 0;

  for (int t = 0; t < TT; ++t){
    const unsigned srec = (unsigned)t & RM;
    const unsigned spub = (unsigned)(t+1) & RM;
    f32x4 acc[4];
#pragma unroll
    for (int g = 0; g < 4; ++g) acc[g] = f32x4{0.f, 0.f, 0.f, 0.f};

    if (layer == 0){
      if (wv == 0){                        // x-term overlaps waits
        const float* xp = x + ((size_t)m16*TT + t)*32 + quad*8;
        bf16x8 ah, al;
#pragma unroll
        for (int j = 0; j < 8; ++j){
          float v = xp[j];
          unsigned short h = f2bf(v);
          ah[j] = (short)h;
          al[j] = (short)f2bf(v - bf2f(h));
        }
#pragma unroll
        for (int g = 0; g < 4; ++g){
          acc[g] = __builtin_amdgcn_mfma_f32_16x16x32_bf16(ah, Bi_hi[g][0], acc[g], 0, 0, 0);
          acc[g] = __builtin_amdgcn_mfma_f32_16x16x32_bf16(al, Bi_hi[g][0], acc[g], 0, 0, 0);
          acc[g] = __builtin_amdgcn_mfma_f32_16x16x32_bf16(ah, Bi_lo[g][0], acc[g], 0, 0, 0);
        }
      }
      // ring backpressure vs layer1 progress (rare)
      while ((long)(t+1) - (long)minp > 250L){
        unsigned v = (lane < 32) ? ld32_lic(PROG + lane) : 0xFFFFFFFFu;
        unsigned m = v;
#pragma unroll
        for (int o = 1; o < 32; o <<= 1){
          unsigned ov = (unsigned)__shfl_xor((int)m, o, 32);
          m = m < ov ? m : ov;
        }
        minp = (unsigned)__shfl((int)m, 0, 64);
        if (--bud < 0) break;
      }
      int got = lmode;
      if (t > 0){
        got = wait_hy(F1L + ((size_t)wv*RING + srec)*32,
                      F1X + ((size_t)wv*RING + srec)*32, (unsigned)t, lane, lmode, bud);
        if (!got) lmode = 0;               // sticky demotion
      }
      const size_t rb = ((size_t)srec*NB + m16)*HH + kwb + quad*8;
      u32x4 r[8];
      if (got) ld8_l2(H1Lh + rb, H1Ll + rb, r);
      else {
#pragma unroll
        for (int c = 0; c < 4; ++c){
          r[c]   = (u32x4)__builtin_bit_cast(u32x4, ld_frag_lic(H1Xh + rb + c*32));
          r[4+c] = (u32x4)__builtin_bit_cast(u32x4, ld_frag_lic(H1Xl + rb + c*32));
        }
      }
#pragma unroll
      for (int c = 0; c < 4; ++c){
        bf16x8 ah = asfrag(r[c]);
        bf16x8 al = asfrag(r[4+c]);
#pragma unroll
        for (int g = 0; g < 4; ++g){
          acc[g] = __builtin_amdgcn_mfma_f32_16x16x32_bf16(ah, Bh_hi[g][c], acc[g], 0, 0, 0);
          acc[g] = __builtin_amdgcn_mfma_f32_16x16x32_bf16(al, Bh_hi[g][c], acc[g], 0, 0, 0);
          acc[g] = __builtin_amdgcn_mfma_f32_16x16x32_bf16(ah, Bh_lo[g][c], acc[g], 0, 0, 0);
        }
      }
    } else {
      // phase 1: layer0's h1(t) via LIC (layer0 runs ahead; usually ready)
      wait_hy(F1X + ((size_t)wv*RING + spub)*32,
              F1X + ((size_t)wv*RING + spub)*32, (unsigned)(t+1), lane, 0, bud);
      {
        const size_t ib = ((size_t)spub*NB + m16)*HH + kwb + quad*8;
#pragma unroll
        for (int c = 0; c < 4; ++c){
          bf16x8 ah = ld_frag_lic(H1Xh + ib + c*32);
          bf16x8 al = ld_frag_lic(H1Xl + ib + c*32);
#pragma unroll
          for (int g = 0; g < 4; ++g){
            acc[g] = __builtin_amdgcn_mfma_f32_16x16x32_bf16(ah, Bi_hi[g][c], acc[g], 0, 0, 0);
            acc[g] = __builtin_amdgcn_mfma_f32_16x16x32_bf16(al, Bi_hi[g][c], acc[g], 0, 0, 0);
            acc[g] = __builtin_amdgcn_mfma_f32_16x16x32_bf16(ah, Bi_lo[g][c], acc[g], 0, 0, 0);
          }
        }
      }
      // phase 2: own recurrence
      int got = lmode;
      if (t > 0){
        got = wait_hy(F2L + ((size_t)wv*RING + srec)*32,
                      F2X + ((size_t)wv*RING + srec)*32, (unsigned)t, lane, lmode, bud);
        if (!got) lmode = 0;
      }
      const size_t rb = ((size_t)srec*NB + m16)*HH + kwb + quad*8;
      u32x4 r[8];
      if (got) ld8_l2(H2Lh + rb, H2Ll + rb, r);
      else {
#pragma unroll
        for (int c = 0; c < 4; ++c){
          r[c]   = (u32x4)__builtin_bit_cast(u32x4, ld_frag_lic(H2Xh + rb + c*32));
          r[4+c] = (u32x4)__builtin_bit_cast(u32x4, ld_frag_lic(H2Xl + rb + c*32));
        }
      }
#pragma unroll
      for (int c = 0; c < 4; ++c){
        bf16x8 ah = asfrag(r[c]);
        bf16x8 al = asfrag(r[4+c]);
#pragma unroll
        for (int g = 0; g < 4; ++g){
          acc[g] = __builtin_amdgcn_mfma_f32_16x16x32_bf16(ah, Bh_hi[g][c], acc[g], 0, 0, 0);
          acc[g] = __builtin_amdgcn_mfma_f32_16x16x32_bf16(al, Bh_hi[g][c], acc[g], 0, 0, 0);
          acc[g] = __builtin_amdgcn_mfma_f32_16x16x32_bf16(ah, Bh_lo[g][c], acc[g], 0, 0, 0);
        }
      }
    }

    // ---- K-reduction via LDS ----
#pragma unroll
    for (int g = 0; g < 4; ++g)
#pragma unroll
      for (int r = 0; r < 4; ++r)
        P[wv][g][quad*4 + r][m16] = acc[g][r];
    __syncthreads();                                   // barrier A

    float G[4];
#pragma unroll
    for (int g = 0; g < 4; ++g)
      G[g] = P[0][g][eb][ej] + P[1][g][eb][ej] + P[2][g][eb][ej] + P[3][g][eb][ej] + bias[g];

    float gi = sigm(G[0]);
    float gf = sigm(G[1]);
    float gc = tanh_f(G[2]);
    float go = sigm(G[3]);
    cst = gf*cst + gi*gc;
    float h = go * tanh_f(cst);

    if (t == TT-1){                                    // before publish (older)
      size_t o = (size_t)layer*NB*HH + (size_t)eb*HH + (j0 + ej);
      out[Y_SZ + o] = h;
      out[Y_SZ + 2*NB*HH + o] = cst;
    }

    // ---- dual publish: plain (XCD L2) first, agent (LIC) second ----
    unsigned short hhi = f2bf(h);
    unsigned short hlo = f2bf(h - bf2f(hhi));
    ull h1s = (ull)(unsigned short)__shfl_down((int)hhi, 1, 64);
    ull h2s = (ull)(unsigned short)__shfl_down((int)hhi, 2, 64);
    ull h3s = (ull)(unsigned short)__shfl_down((int)hhi, 3, 64);
    ull l1s = (ull)(unsigned short)__shfl_down((int)hlo, 1, 64);
    ull l2s = (ull)(unsigned short)__shfl_down((int)hlo, 2, 64);
    ull l3s = (ull)(unsigned short)__shfl_down((int)hlo, 3, 64);
    if ((ej & 3) == 0){
      ull vh = (ull)hhi | (h1s << 16) | (h2s << 32) | (h3s << 48);
      ull vl = (ull)hlo | (l1s << 16) | (l2s << 32) | (l3s << 48);
      size_t pr = (((size_t)spub*NB + eb)*HH + (unsigned)(j0 + ej)) >> 2;
      if (layer == 0){
        st64_pl((ull*)H1Lh + pr, vh);
        st64_pl((ull*)H1Ll + pr, vl);
        st64_lic((ull*)H1Xh + pr, vh);
        st64_lic((ull*)H1Xl + pr, vl);
      } else {
        size_t pf = (((size_t)t*NB + eb)*HH + (unsigned)(j0 + ej)) >> 2;
        st64_pl((ull*)H2Lh + pr, vh);
        st64_pl((ull*)H2Ll + pr, vl);
        st64_pl((ull*)H2Fh + pf, vh);
        st64_pl((ull*)H2Fl + pf, vl);
        st64_lic((ull*)H2Xh + pr, vh);
        st64_lic((ull*)H2Xl + pr, vl);
      }
    }

    // certify plain stores only (2 youngest = agent; in-order vmcnt)
    asm volatile("s_waitcnt vmcnt(2)" ::: "memory");
    __syncthreads();                                   // barrier B
    if (tid == 0){
      unsigned val = (unsigned)(t+1);
      unsigned* FL = layer ? F2L : F1L;
#pragma unroll
      for (int r2 = 0; r2 < 4; ++r2)
        st32_pl(FL + ((size_t)r2*RING + spub)*32 + sl, val);
    }
    // certify agent stores, then LIC flags
    asm volatile("s_waitcnt vmcnt(0)" ::: "memory");
    __syncthreads();                                   // barrier C
    if (tid == 0){
      unsigned val = (unsigned)(t+1);
      unsigned* FX = layer ? F2X : F1X;
#pragma unroll
      for (int r2 = 0; r2 < 4; ++r2)
        st32_lic(FX + ((size_t)r2*RING + spub)*32 + sl, val);
      if (layer) st32_lic(PROG + sl, val);
    }
  }
}

// =====================================================================
// y = h2 @ w_out^T + b_out   (parallel epilogue, one block per timestep)
// =====================================================================
__global__ __launch_bounds__(256, 1) void y_proj(
    const unsigned short* __restrict__ Hhi2, const unsigned short* __restrict__ Hlo2,
    const float* __restrict__ w_out, const float* __restrict__ b_out,
    float* __restrict__ out)
{
  __shared__ float hsh[NB][HH + 1];
  __shared__ float wsh[32][HH + 1];
  const int tid = threadIdx.x;
  const int t = blockIdx.x;

  for (int i = tid; i < 32*HH; i += 256){
    int o = i >> 9, k = i & (HH-1);
    wsh[o][k] = w_out[i];
  }
  for (int i = tid; i < NB*HH; i += 256){
    int b = i >> 9, k = i & (HH-1);
    size_t off = ((size_t)t*NB + b)*HH + k;
    hsh[b][k] = bf2f(Hhi2[off]) + bf2f(Hlo2[off]);
  }
  __syncthreads();

  const int o = tid & 31, bg = tid >> 5;
  float a0 = 0.f, a1 = 0.f;
  for (int k = 0; k < HH; ++k){
    float w = wsh[o][k];
    a0 += w * hsh[bg][k];
    a1 += w * hsh[bg + 8][k];
  }
  float bo = b_out[o];
  out[((size_t)bg*TT + t)*32 + o] = a0 + bo;
  out[((size_t)(bg+8)*TT + t)*32 + o] = a1 + bo;
}

extern "C" void kernel_launch(void* const* d_in, const int* in_sizes, int n_in,
                              void* d_out, int out_size, void* d_ws, size_t ws_size,
                              hipStream_t stream)
{
  (void)in_sizes; (void)n_in; (void)out_size;
  const float* x     = (const float*)d_in[0];
  const float* w_ih0 = (const float*)d_in[1];
  const float* w_hh0 = (const float*)d_in[2];
  const float* b_ih0 = (const float*)d_in[3];
  const float* b_hh0 = (const float*)d_in[4];
  const float* w_ih1 = (const float*)d_in[5];
  const float* w_hh1 = (const float*)d_in[6];
  const float* b_ih1 = (const float*)d_in[7];
  const float* b_hh1 = (const float*)d_in[8];
  const float* w_out = (const float*)d_in[9];
  const float* b_out = (const float*)d_in[10];
  float* out = (float*)d_out;
  unsigned char* ws = (unsigned char*)d_ws;

  if (ws_size < WS_NEED) return;   // clean validation failure if too small

  // zero control region + slot 0 of all ring arrays (h(0) = 0)
  hipMemsetAsync(ws, 0, OFF_ZEND, stream);
  hipMemsetAsync(ws + OFF_H1LH, 0, RSLOT*2, stream);
  hipMemsetAsync(ws + OFF_H1LL, 0, RSLOT*2, stream);
  hipMemsetAsync(ws + OFF_H1XH, 0, RSLOT*2, stream);
  hipMemsetAsync(ws + OFF_H1XL, 0, RSLOT*2, stream);
  hipMemsetAsync(ws + OFF_H2LH, 0, RSLOT*2, stream);
  hipMemsetAsync(ws + OFF_H2LL, 0, RSLOT*2, stream);
  hipMemsetAsync(ws + OFF_H2XH, 0, RSLOT*2, stream);
  hipMemsetAsync(ws + OFF_H2XL, 0, RSLOT*2, stream);

  lstm_persist<<<dim3(512), dim3(256), 0, stream>>>(
      x, w_ih0, w_hh0, b_ih0, b_hh0, w_ih1, w_hh1, b_ih1, b_hh1, out, ws);

  const unsigned short* H2Fh = (const unsigned short*)(ws + OFF_H2FH);
  const unsigned short* H2Fl = (const unsigned short*)(ws + OFF_H2FL);
  y_proj<<<dim3(TT), dim3(256), 0, stream>>>(H2Fh, H2Fl, w_out, b_out, out);
}

// Round 9
// 9686.996 us; speedup vs baseline: 1.4512x; 1.1129x over previous
//
#include <hip/hip_runtime.h>

// ---------------- problem constants ----------------
#define TT   2048
#define NB   16
#define HH   512
#define NSL  32            // WG slices per layer
#define HSL  16            // hidden units per slice
#define KW   128           // K-range per wave
#define Y_SZ (NB*TT*32)
#define RING 256
#define RM   255

typedef __attribute__((ext_vector_type(8))) short bf16x8;
typedef __attribute__((ext_vector_type(4))) float f32x4;
typedef __attribute__((ext_vector_type(4))) unsigned u32x4;
typedef unsigned long long ull;

// ---------------- workspace layout (bytes) ----------------
#define OFF_XCCV 0u
#define OFF_MODE 256u
#define OFF_PROG 512u
#define OFF_F1L  4096u
#define FLB      (4u*RING*32u*4u)
#define OFF_F1X  (OFF_F1L + FLB)
#define OFF_F2L  (OFF_F1X + FLB)
#define OFF_F2X  (OFF_F2L + FLB)
#define OFF_ZEND (OFF_F2X + FLB)
#define RSLOT    ((size_t)NB*HH)
#define RB       ((size_t)RING*RSLOT*2)
#define OFF_H1LH ((size_t)(1u<<20))
#define OFF_H1LL (OFF_H1LH + RB)
#define OFF_H1XH (OFF_H1LL + RB)
#define OFF_H1XL (OFF_H1XH + RB)
#define OFF_H2LH (OFF_H1XL + RB)
#define OFF_H2LL (OFF_H2LH + RB)
#define OFF_H2XH (OFF_H2LL + RB)
#define OFF_H2XL (OFF_H2XH + RB)
#define FB       ((size_t)TT*RSLOT*2)
#define OFF_H2FH (OFF_H2XL + RB)
#define OFF_H2FL (OFF_H2FH + FB)
#define WS_NEED  (OFF_H2FL + FB)

__device__ __forceinline__ unsigned short f2bf(float x){
  unsigned u = __float_as_uint(x);
  return (unsigned short)((u + 0x7FFFu + ((u >> 16) & 1u)) >> 16);
}
__device__ __forceinline__ float bf2f(unsigned short b){
  return __uint_as_float(((unsigned)b) << 16);
}
__device__ __forceinline__ float sigm(float v){ return 1.0f / (1.0f + __expf(-v)); }
__device__ __forceinline__ float tanh_f(float v){
  float a = fabsf(v);
  float e = __expf(-2.0f * a);
  float t = (1.0f - e) / (1.0f + e);
  return v < 0.0f ? -t : t;
}
__device__ __forceinline__ void split8(const float* __restrict__ p, bf16x8& hi, bf16x8& lo){
#pragma unroll
  for (int j = 0; j < 8; ++j){
    float w = p[j];
    unsigned short h = f2bf(w);
    hi[j] = (short)h;
    lo[j] = (short)f2bf(w - bf2f(h));
  }
}
__device__ __forceinline__ bf16x8 mk(ull a, ull b){
  union { ull u[2]; bf16x8 v; } r; r.u[0] = a; r.u[1] = b; return r.v;
}
__device__ __forceinline__ bf16x8 asfrag(u32x4 v){
  union { u32x4 u; bf16x8 b; } r; r.u = v; return r.b;
}
// ---- LIC (agent-scope) primitives ----
__device__ __forceinline__ ull ld64_lic(const ull* p){
  return __hip_atomic_load(p, __ATOMIC_RELAXED, __HIP_MEMORY_SCOPE_AGENT);
}
__device__ __forceinline__ unsigned ld32_lic(const unsigned* p){
  return __hip_atomic_load(p, __ATOMIC_RELAXED, __HIP_MEMORY_SCOPE_AGENT);
}
__device__ __forceinline__ void st64_lic(ull* p, ull v){
  __hip_atomic_store(p, v, __ATOMIC_RELAXED, __HIP_MEMORY_SCOPE_AGENT);
}
__device__ __forceinline__ void st32_lic(unsigned* p, unsigned v){
  __hip_atomic_store(p, v, __ATOMIC_RELAXED, __HIP_MEMORY_SCOPE_AGENT);
}
__device__ __forceinline__ bf16x8 ld_frag_lic(const unsigned short* p){
  return mk(ld64_lic((const ull*)p), ld64_lic((const ull*)p + 1));
}
// ---- XCD-local primitives: L1 invalidate + plain (L2-served) access ----
__device__ __forceinline__ unsigned ld32_l2(const unsigned* p){
  unsigned r;
  asm volatile("buffer_inv sc0\n\t"
               "global_load_dword %0, %1, off\n\t"
               "s_waitcnt vmcnt(0)"
               : "=&v"(r) : "v"(p) : "memory");
  return r;
}
__device__ __forceinline__ void ld8_l2(const void* ph, const void* pl, u32x4* r){
  asm volatile(
    "buffer_inv sc0\n\t"
    "global_load_dwordx4 %0, %8, off\n\t"
    "global_load_dwordx4 %1, %8, off offset:64\n\t"
    "global_load_dwordx4 %2, %8, off offset:128\n\t"
    "global_load_dwordx4 %3, %8, off offset:192\n\t"
    "global_load_dwordx4 %4, %9, off\n\t"
    "global_load_dwordx4 %5, %9, off offset:64\n\t"
    "global_load_dwordx4 %6, %9, off offset:128\n\t"
    "global_load_dwordx4 %7, %9, off offset:192\n\t"
    "s_waitcnt vmcnt(0)"
    : "=&v"(r[0]),"=&v"(r[1]),"=&v"(r[2]),"=&v"(r[3]),
      "=&v"(r[4]),"=&v"(r[5]),"=&v"(r[6]),"=&v"(r[7])
    : "v"(ph), "v"(pl) : "memory");
}
// batched LIC loads, FULLY WAITED inside the block
__device__ __forceinline__ void ld8_lic(const void* ph, const void* pl, u32x4* r){
  asm volatile(
    "global_load_dwordx4 %0, %8, off sc0 sc1\n\t"
    "global_load_dwordx4 %1, %8, off offset:64 sc0 sc1\n\t"
    "global_load_dwordx4 %2, %8, off offset:128 sc0 sc1\n\t"
    "global_load_dwordx4 %3, %8, off offset:192 sc0 sc1\n\t"
    "global_load_dwordx4 %4, %9, off sc0 sc1\n\t"
    "global_load_dwordx4 %5, %9, off offset:64 sc0 sc1\n\t"
    "global_load_dwordx4 %6, %9, off offset:128 sc0 sc1\n\t"
    "global_load_dwordx4 %7, %9, off offset:192 sc0 sc1\n\t"
    "s_waitcnt vmcnt(0)"
    : "=&v"(r[0]),"=&v"(r[1]),"=&v"(r[2]),"=&v"(r[3]),
      "=&v"(r[4]),"=&v"(r[5]),"=&v"(r[6]),"=&v"(r[7])
    : "v"(ph), "v"(pl) : "memory");
}
__device__ __forceinline__ void st64_pl(void* p, ull v){
  asm volatile("global_store_dwordx2 %0, %1, off" :: "v"(p), "v"(v) : "memory");
}
__device__ __forceinline__ void st32_pl(unsigned* p, unsigned v){
  asm volatile("global_store_dword %0, %1, off" :: "v"(p), "v"(v) : "memory");
}

// local flag wait with LIC cross-check; >= compare (values monotone, ring
// backpressure bounds producer lead < RING so no false wrap match).
// 1 = local ok, 0 = use LIC path
__device__ __forceinline__ int wait_hy(const unsigned* bL, const unsigned* bX,
                                       unsigned expect, int lane, int lmode, long& bud){
  if (!lmode){
    bool ok = (lane >= 32);
    while (__ballot(!ok) != 0ULL){
      if (!ok) ok = (ld32_lic(bX + lane) >= expect);
      if (--bud < 0) return 0;
    }
    return 0;
  }
  bool okL = (lane >= 32);
  int k = 0;
  while (true){
    if (__ballot(!okL) == 0ULL) return 1;
    if (!okL) okL = (ld32_l2(bL + lane) >= expect);
    if ((++k & 15) == 0){
      bool okX = (lane >= 32);
      if (!okX) okX = (ld32_lic(bX + lane) >= expect);
      if (__ballot(!okX) == 0ULL){
        if (!okL) okL = (ld32_l2(bL + lane) >= expect);
        return (__ballot(!okL) == 0ULL) ? 1 : 0;
      }
    }
    if (--bud < 0) return 0;
  }
}
// LIC-only value wait
__device__ __forceinline__ void wait_lic(const unsigned* bX, unsigned expect, int lane, long& bud){
  bool ok = (lane >= 32);
  while (__ballot(!ok) != 0ULL){
    if (!ok) ok = (ld32_lic(bX + lane) >= expect);
    if (--bud < 0) return;
  }
}

// =====================================================================
// Persistent 2-layer LSTM, XCD-local coherence — r6 protocol VERBATIM
// (in-loop vmcnt(0)+barrier C LIC flag publication; NO deferral) plus
// ONLY the layer1 input software pipeline (preamble + post-publish tail,
// fully-waited loads). Bisection round: isolates the tail change.
// =====================================================================
__global__ __launch_bounds__(256, 1) void lstm_persist(
    const float* __restrict__ x,
    const float* __restrict__ w_ih0, const float* __restrict__ w_hh0,
    const float* __restrict__ b_ih0, const float* __restrict__ b_hh0,
    const float* __restrict__ w_ih1, const float* __restrict__ w_hh1,
    const float* __restrict__ b_ih1, const float* __restrict__ b_hh1,
    float* __restrict__ out, unsigned char* __restrict__ ws)
{
  unsigned* XCCV = (unsigned*)(ws + OFF_XCCV);
  unsigned* MODE = (unsigned*)(ws + OFF_MODE);
  unsigned* PROG = (unsigned*)(ws + OFF_PROG);
  unsigned* F1L  = (unsigned*)(ws + OFF_F1L);
  unsigned* F1X  = (unsigned*)(ws + OFF_F1X);
  unsigned* F2L  = (unsigned*)(ws + OFF_F2L);
  unsigned* F2X  = (unsigned*)(ws + OFF_F2X);
  unsigned short* H1Lh = (unsigned short*)(ws + OFF_H1LH);
  unsigned short* H1Ll = (unsigned short*)(ws + OFF_H1LL);
  unsigned short* H1Xh = (unsigned short*)(ws + OFF_H1XH);
  unsigned short* H1Xl = (unsigned short*)(ws + OFF_H1XL);
  unsigned short* H2Lh = (unsigned short*)(ws + OFF_H2LH);
  unsigned short* H2Ll = (unsigned short*)(ws + OFF_H2LL);
  unsigned short* H2Xh = (unsigned short*)(ws + OFF_H2XH);
  unsigned short* H2Xl = (unsigned short*)(ws + OFF_H2XL);
  unsigned short* H2Fh = (unsigned short*)(ws + OFF_H2FH);
  unsigned short* H2Fl = (unsigned short*)(ws + OFF_H2FL);

  const int tid  = threadIdx.x;
  const int lane = tid & 63;
  const int wv   = tid >> 6;
  const int m16  = lane & 15;
  const int quad = lane >> 4;

  const int bid = blockIdx.x;
  const int xs  = bid & 7;
  const int pos = bid >> 3;
  if (xs >= 2 || pos >= NSL) return;
  const int layer = xs;
  const int sl    = pos;
  const int role  = layer * NSL + sl;
  const int j0    = sl * HSL;
  const int kwb   = wv * KW;

  long bud = 3000000;

  // ---- placement verification (r6) ----
  if (tid == 0){
    unsigned xcc = 0xDEAD;
    asm volatile("s_getreg_b32 %0, hwreg(HW_REG_XCC_ID)" : "=s"(xcc));
    st32_lic(XCCV + role, (xcc & 255u) | 0x100u);
  }
  __syncthreads();
  if (bid == 0 && wv == 0){
    bool got = false; unsigned v = 0;
    long b2 = 2000000;
    while (true){
      if (!got){ v = ld32_lic(XCCV + lane); got = (v & 0x100u) != 0u; }
      if (__ballot(!got) == 0ULL) break;
      if (--b2 < 0) break;
    }
    unsigned v0  = (unsigned)__shfl((int)v, 0, 64);
    unsigned v32 = (unsigned)__shfl((int)v, 32, 64);
    bool ok = got && ((lane < 32) ? (v == v0) : (v == v32));
    unsigned mode = (__ballot(!ok) == 0ULL) ? 1u : 0u;
    if (lane == 0) st32_lic(MODE, mode | 0x100u);
  }
  __shared__ unsigned s_mode;
  if (tid == 0){
    unsigned m = 0; long b3 = 2000000;
    do { m = ld32_lic(MODE); } while (!(m & 0x100u) && --b3 > 0);
    s_mode = m;
  }
  __syncthreads();
  int lmode = ((s_mode & 0x100u) && (s_mode & 1u)) ? 1 : 0;

  const float* Wh  = layer ? w_hh1 : w_hh0;
  const float* biL = layer ? b_ih1 : b_ih0;
  const float* bhL = layer ? b_hh1 : b_hh0;

  bf16x8 Bh_hi[4][4], Bh_lo[4][4];
#pragma unroll
  for (int g = 0; g < 4; ++g)
#pragma unroll
    for (int c = 0; c < 4; ++c){
      int row = g*HH + j0 + m16;
      int k0  = kwb + c*32 + quad*8;
      split8(Wh + (size_t)row*HH + k0, Bh_hi[g][c], Bh_lo[g][c]);
    }
  bf16x8 Bi_hi[4][4], Bi_lo[4][4];
  if (layer){
#pragma unroll
    for (int g = 0; g < 4; ++g)
#pragma unroll
      for (int c = 0; c < 4; ++c){
        int row = g*HH + j0 + m16;
        int k0  = kwb + c*32 + quad*8;
        split8(w_ih1 + (size_t)row*HH + k0, Bi_hi[g][c], Bi_lo[g][c]);
      }
  } else if (wv == 0){
#pragma unroll
    for (int g = 0; g < 4; ++g){
      int row = g*HH + j0 + m16;
      split8(w_ih0 + (size_t)row*32 + quad*8, Bi_hi[g][0], Bi_lo[g][0]);
    }
  }

  const int eb = tid >> 4;
  const int ej = tid & 15;
  float bias[4];
#pragma unroll
  for (int g = 0; g < 4; ++g){
    int r = g*HH + j0 + ej;
    bias[g] = biL[r] + bhL[r];
  }

  float cst = 0.0f;
  __shared__ float P[4][4][16][16];
  unsigned minp = 0;

  // ---- layer1 preamble: input matmul for step 0 (h1(0) = H1X slot 1) ----
  f32x4 accIn[4];
#pragma unroll
  for (int g = 0; g < 4; ++g) accIn[g] = f32x4{0.f, 0.f, 0.f, 0.f};
  if (layer){
    wait_lic(F1X + ((size_t)wv*RING + 1)*32, 1u, lane, bud);
    const size_t ib = ((size_t)1*NB + m16)*HH + kwb + quad*8;
    u32x4 r[8];
    ld8_lic(H1Xh + ib, H1Xl + ib, r);
#pragma unroll
    for (int c = 0; c < 4; ++c){
      bf16x8 ah = asfrag(r[c]);
      bf16x8 al = asfrag(r[4+c]);
#pragma unroll
      for (int g = 0; g < 4; ++g){
        accIn[g] = __builtin_amdgcn_mfma_f32_16x16x32_bf16(ah, Bi_hi[g][c], accIn[g], 0, 0, 0);
        accIn[g] = __builtin_amdgcn_mfma_f32_16x16x32_bf16(al, Bi_hi[g][c], accIn[g], 0, 0, 0);
        accIn[g] = __builtin_amdgcn_mfma_f32_16x16x32_bf16(ah, Bi_lo[g][c], accIn[g], 0, 0, 0);
      }
    }
  }

  for (int t = 0; t < TT; ++t){
    const unsigned srec = (unsigned)t & RM;
    const unsigned spub = (unsigned)(t+1) & RM;
    f32x4 acc[4];

    if (layer == 0){
#pragma unroll
      for (int g = 0; g < 4; ++g) acc[g] = f32x4{0.f, 0.f, 0.f, 0.f};
      if (wv == 0){                        // x-term overlaps waits
        const float* xp = x + ((size_t)m16*TT + t)*32 + quad*8;
        bf16x8 ah, al;
#pragma unroll
        for (int j = 0; j < 8; ++j){
          float v = xp[j];
          unsigned short h = f2bf(v);
          ah[j] = (short)h;
          al[j] = (short)f2bf(v - bf2f(h));
        }
#pragma unroll
        for (int g = 0; g < 4; ++g){
          acc[g] = __builtin_amdgcn_mfma_f32_16x16x32_bf16(ah, Bi_hi[g][0], acc[g], 0, 0, 0);
          acc[g] = __builtin_amdgcn_mfma_f32_16x16x32_bf16(al, Bi_hi[g][0], acc[g], 0, 0, 0);
          acc[g] = __builtin_amdgcn_mfma_f32_16x16x32_bf16(ah, Bi_lo[g][0], acc[g], 0, 0, 0);
        }
      }
      while ((long)(t+1) - (long)minp > 248L){          // ring backpressure
        unsigned v = (lane < 32) ? ld32_lic(PROG + lane) : 0xFFFFFFFFu;
        unsigned m = v;
#pragma unroll
        for (int o = 1; o < 32; o <<= 1){
          unsigned ov = (unsigned)__shfl_xor((int)m, o, 32);
          m = m < ov ? m : ov;
        }
        minp = (unsigned)__shfl((int)m, 0, 64);
        if (--bud < 0) break;
      }
      int got = lmode;
      if (t > 0){
        got = wait_hy(F1L + ((size_t)wv*RING + srec)*32,
                      F1X + ((size_t)wv*RING + srec)*32, (unsigned)t, lane, lmode, bud);
        if (!got) lmode = 0;
      }
      const size_t rb = ((size_t)srec*NB + m16)*HH + kwb + quad*8;
      u32x4 r[8];
      if (got) ld8_l2(H1Lh + rb, H1Ll + rb, r);
      else {
#pragma unroll
        for (int c = 0; c < 4; ++c){
          r[c]   = (u32x4)__builtin_bit_cast(u32x4, ld_frag_lic(H1Xh + rb + c*32));
          r[4+c] = (u32x4)__builtin_bit_cast(u32x4, ld_frag_lic(H1Xl + rb + c*32));
        }
      }
#pragma unroll
      for (int c = 0; c < 4; ++c){
        bf16x8 ah = asfrag(r[c]);
        bf16x8 al = asfrag(r[4+c]);
#pragma unroll
        for (int g = 0; g < 4; ++g){
          acc[g] = __builtin_amdgcn_mfma_f32_16x16x32_bf16(ah, Bh_hi[g][c], acc[g], 0, 0, 0);
          acc[g] = __builtin_amdgcn_mfma_f32_16x16x32_bf16(al, Bh_hi[g][c], acc[g], 0, 0, 0);
          acc[g] = __builtin_amdgcn_mfma_f32_16x16x32_bf16(ah, Bh_lo[g][c], acc[g], 0, 0, 0);
        }
      }
    } else {
      // acc starts from the pipelined input matmul (h1(t) @ W_ih1^T)
#pragma unroll
      for (int g = 0; g < 4; ++g) acc[g] = accIn[g];
      int got = lmode;
      if (t > 0){
        got = wait_hy(F2L + ((size_t)wv*RING + srec)*32,
                      F2X + ((size_t)wv*RING + srec)*32, (unsigned)t, lane, lmode, bud);
        if (!got) lmode = 0;
      }
      const size_t rb = ((size_t)srec*NB + m16)*HH + kwb + quad*8;
      u32x4 r[8];
      if (got) ld8_l2(H2Lh + rb, H2Ll + rb, r);
      else {
#pragma unroll
        for (int c = 0; c < 4; ++c){
          r[c]   = (u32x4)__builtin_bit_cast(u32x4, ld_frag_lic(H2Xh + rb + c*32));
          r[4+c] = (u32x4)__builtin_bit_cast(u32x4, ld_frag_lic(H2Xl + rb + c*32));
        }
      }
#pragma unroll
      for (int c = 0; c < 4; ++c){
        bf16x8 ah = asfrag(r[c]);
        bf16x8 al = asfrag(r[4+c]);
#pragma unroll
        for (int g = 0; g < 4; ++g){
          acc[g] = __builtin_amdgcn_mfma_f32_16x16x32_bf16(ah, Bh_hi[g][c], acc[g], 0, 0, 0);
          acc[g] = __builtin_amdgcn_mfma_f32_16x16x32_bf16(al, Bh_hi[g][c], acc[g], 0, 0, 0);
          acc[g] = __builtin_amdgcn_mfma_f32_16x16x32_bf16(ah, Bh_lo[g][c], acc[g], 0, 0, 0);
        }
      }
    }

    // ---- K-reduction via LDS ----
#pragma unroll
    for (int g = 0; g < 4; ++g)
#pragma unroll
      for (int r = 0; r < 4; ++r)
        P[wv][g][quad*4 + r][m16] = acc[g][r];
    __syncthreads();                                   // barrier A

    float G[4];
#pragma unroll
    for (int g = 0; g < 4; ++g)
      G[g] = P[0][g][eb][ej] + P[1][g][eb][ej] + P[2][g][eb][ej] + P[3][g][eb][ej] + bias[g];

    float gi = sigm(G[0]);
    float gf = sigm(G[1]);
    float gc = tanh_f(G[2]);
    float go = sigm(G[3]);
    cst = gf*cst + gi*gc;
    float h = go * tanh_f(cst);

    if (t == TT-1){
      size_t o = (size_t)layer*NB*HH + (size_t)eb*HH + (j0 + ej);
      out[Y_SZ + o] = h;
      out[Y_SZ + 2*NB*HH + o] = cst;
    }

    // ---- dual publish: plain (XCD L2) first, agent (LIC) second ----
    unsigned short hhi = f2bf(h);
    unsigned short hlo = f2bf(h - bf2f(hhi));
    ull h1s = (ull)(unsigned short)__shfl_down((int)hhi, 1, 64);
    ull h2s = (ull)(unsigned short)__shfl_down((int)hhi, 2, 64);
    ull h3s = (ull)(unsigned short)__shfl_down((int)hhi, 3, 64);
    ull l1s = (ull)(unsigned short)__shfl_down((int)hlo, 1, 64);
    ull l2s = (ull)(unsigned short)__shfl_down((int)hlo, 2, 64);
    ull l3s = (ull)(unsigned short)__shfl_down((int)hlo, 3, 64);
    if ((ej & 3) == 0){
      ull vh = (ull)hhi | (h1s << 16) | (h2s << 32) | (h3s << 48);
      ull vl = (ull)hlo | (l1s << 16) | (l2s << 32) | (l3s << 48);
      size_t pr = (((size_t)spub*NB + eb)*HH + (unsigned)(j0 + ej)) >> 2;
      if (layer == 0){
        st64_pl((ull*)H1Lh + pr, vh);
        st64_pl((ull*)H1Ll + pr, vl);
        st64_lic((ull*)H1Xh + pr, vh);
        st64_lic((ull*)H1Xl + pr, vl);
      } else {
        size_t pf_ = (((size_t)t*NB + eb)*HH + (unsigned)(j0 + ej)) >> 2;
        st64_pl((ull*)H2Lh + pr, vh);
        st64_pl((ull*)H2Ll + pr, vl);
        st64_pl((ull*)H2Fh + pf_, vh);
        st64_pl((ull*)H2Fl + pf_, vl);
        st64_lic((ull*)H2Xh + pr, vh);
        st64_lic((ull*)H2Xl + pr, vl);
      }
    }

    // r6 protocol verbatim: two-stage drain + flag publication
    asm volatile("s_waitcnt vmcnt(2)" ::: "memory");   // certify plain stores
    __syncthreads();                                   // barrier B
    if (tid == 0){
      unsigned val = (unsigned)(t+1);
      unsigned* FL = layer ? F2L : F1L;
#pragma unroll
      for (int r2 = 0; r2 < 4; ++r2)
        st32_pl(FL + ((size_t)r2*RING + spub)*32 + sl, val);
    }
    asm volatile("s_waitcnt vmcnt(0)" ::: "memory");   // certify agent stores
    __syncthreads();                                   // barrier C
    if (tid == 0){
      unsigned val = (unsigned)(t+1);
      unsigned* FX = layer ? F2X : F1X;
#pragma unroll
      for (int r2 = 0; r2 < 4; ++r2)
        st32_lic(FX + ((size_t)r2*RING + spub)*32 + sl, val);
      if (layer) st32_lic(PROG + sl, val);
    }

    // ---- layer1 pipeline tail: input matmul for step t+1 (WAITED loads);
    //      runs after own flags are out, overlapping flag propagation ----
    if (layer && t + 1 < TT){
#pragma unroll
      for (int g = 0; g < 4; ++g) accIn[g] = f32x4{0.f, 0.f, 0.f, 0.f};
      const unsigned nslot = (unsigned)(t+2) & RM;
      wait_lic(F1X + ((size_t)wv*RING + nslot)*32, (unsigned)(t+2), lane, bud);
      const size_t nb_ = ((size_t)nslot*NB + m16)*HH + kwb + quad*8;
      u32x4 r[8];
      ld8_lic(H1Xh + nb_, H1Xl + nb_, r);
#pragma unroll
      for (int c = 0; c < 4; ++c){
        bf16x8 ah = asfrag(r[c]);
        bf16x8 al = asfrag(r[4+c]);
#pragma unroll
        for (int g = 0; g < 4; ++g){
          accIn[g] = __builtin_amdgcn_mfma_f32_16x16x32_bf16(ah, Bi_hi[g][c], accIn[g], 0, 0, 0);
          accIn[g] = __builtin_amdgcn_mfma_f32_16x16x32_bf16(al, Bi_hi[g][c], accIn[g], 0, 0, 0);
          accIn[g] = __builtin_amdgcn_mfma_f32_16x16x32_bf16(ah, Bi_lo[g][c], accIn[g], 0, 0, 0);
        }
      }
    }
  }
}

// =====================================================================
// y = h2 @ w_out^T + b_out   (parallel epilogue, one block per timestep)
// =====================================================================
__global__ __launch_bounds__(256, 1) void y_proj(
    const unsigned short* __restrict__ Hhi2, const unsigned short* __restrict__ Hlo2,
    const float* __restrict__ w_out, const float* __restrict__ b_out,
    float* __restrict__ out)
{
  __shared__ float hsh[NB][HH + 1];
  __shared__ float wsh[32][HH + 1];
  const int tid = threadIdx.x;
  const int t = blockIdx.x;

  for (int i = tid; i < 32*HH; i += 256){
    int o = i >> 9, k = i & (HH-1);
    wsh[o][k] = w_out[i];
  }
  for (int i = tid; i < NB*HH; i += 256){
    int b = i >> 9, k = i & (HH-1);
    size_t off = ((size_t)t*NB + b)*HH + k;
    hsh[b][k] = bf2f(Hhi2[off]) + bf2f(Hlo2[off]);
  }
  __syncthreads();

  const int o = tid & 31, bg = tid >> 5;
  float a0 = 0.f, a1 = 0.f;
  for (int k = 0; k < HH; ++k){
    float w = wsh[o][k];
    a0 += w * hsh[bg][k];
    a1 += w * hsh[bg + 8][k];
  }
  float bo = b_out[o];
  out[((size_t)bg*TT + t)*32 + o] = a0 + bo;
  out[((size_t)(bg+8)*TT + t)*32 + o] = a1 + bo;
}

extern "C" void kernel_launch(void* const* d_in, const int* in_sizes, int n_in,
                              void* d_out, int out_size, void* d_ws, size_t ws_size,
                              hipStream_t stream)
{
  (void)in_sizes; (void)n_in; (void)out_size;
  const float* x     = (const float*)d_in[0];
  const float* w_ih0 = (const float*)d_in[1];
  const float* w_hh0 = (const float*)d_in[2];
  const float* b_ih0 = (const float*)d_in[3];
  const float* b_hh0 = (const float*)d_in[4];
  const float* w_ih1 = (const float*)d_in[5];
  const float* w_hh1 = (const float*)d_in[6];
  const float* b_ih1 = (const float*)d_in[7];
  const float* b_hh1 = (const float*)d_in[8];
  const float* w_out = (const float*)d_in[9];
  const float* b_out = (const float*)d_in[10];
  float* out = (float*)d_out;
  unsigned char* ws = (unsigned char*)d_ws;

  if (ws_size < WS_NEED) return;

  hipMemsetAsync(ws, 0, OFF_ZEND, stream);
  hipMemsetAsync(ws + OFF_H1LH, 0, RSLOT*2, stream);
  hipMemsetAsync(ws + OFF_H1LL, 0, RSLOT*2, stream);
  hipMemsetAsync(ws + OFF_H1XH, 0, RSLOT*2, stream);
  hipMemsetAsync(ws + OFF_H1XL, 0, RSLOT*2, stream);
  hipMemsetAsync(ws + OFF_H2LH, 0, RSLOT*2, stream);
  hipMemsetAsync(ws + OFF_H2LL, 0, RSLOT*2, stream);
  hipMemsetAsync(ws + OFF_H2XH, 0, RSLOT*2, stream);
  hipMemsetAsync(ws + OFF_H2XL, 0, RSLOT*2, stream);

  lstm_persist<<<dim3(512), dim3(256), 0, stream>>>(
      x, w_ih0, w_hh0, b_ih0, b_hh0, w_ih1, w_hh1, b_ih1, b_hh1, out, ws);

  const unsigned short* H2Fh = (const unsigned short*)(ws + OFF_H2FH);
  const unsigned short* H2Fl = (const unsigned short*)(ws + OFF_H2FL);
  y_proj<<<dim3(TT), dim3(256), 0, stream>>>(H2Fh, H2Fl, w_out, b_out, out);
}